// Round 5
// baseline (218.741 us; speedup 1.0000x reference)
//
#include <hip/hip_runtime.h>

namespace {
constexpr int IMG_W = 512, IMG_H = 512;
constexpr int TW = 32, TH = 32;
constexpr int IN_H = TH + 10;           // 42 h-rows
constexpr float C1c = 0.01f * 0.01f;
constexpr float C2c = 0.03f * 0.03f;

constexpr float GW[11] = {
    1.0283799e-03f, 7.5987582e-03f, 3.6000773e-02f, 1.0936069e-01f,
    2.1300554e-01f, 2.6601172e-01f, 2.1300554e-01f, 1.0936069e-01f,
    3.6000773e-02f, 7.5987582e-03f, 1.0283799e-03f
};

using v2f = __attribute__((ext_vector_type(2))) float;
using v4f = __attribute__((ext_vector_type(4))) float;

// In-place packed FMA, weight in SGPR pair: acc += w * a.
__device__ __forceinline__ void pkfma(v2f& acc, v2f w, v2f a) {
    asm("v_pk_fma_f32 %0, %1, %2, %0" : "+v"(acc) : "s"(w), "v"(a));
}
// d = a*b + c (all VGPR pairs).
__device__ __forceinline__ v2f pkfma3(v2f a, v2f b, v2f c) {
    v2f d;
    asm("v_pk_fma_f32 %0, %1, %2, %3" : "=v"(d) : "v"(a), "v"(b), "v"(c));
    return d;
}
__device__ __forceinline__ v2f pkmul(v2f a, v2f b) {
    v2f d;
    asm("v_pk_mul_f32 %0, %1, %2" : "=v"(d) : "v"(a), "v"(b));
    return d;
}
__device__ __forceinline__ v2f pkadd(v2f a, v2f b) {
    v2f d;
    asm("v_pk_add_f32 %0, %1, %2" : "=v"(d) : "v"(a), "v"(b));
    return d;
}
__device__ __forceinline__ v2f bcast(float w) { v2f r; r.x = w; r.y = w; return r; }

// h-plane rotate swizzle: 16 v4f per row, entry = row*16 + ((pc+row)&15).
// Bank granule = (pc+row) mod 8 -> phase-A writes (pc=4gA+jp, row=rA) and
// P3 reads (pc=tid&15, row=rb+k) both spread 8 lanes per 16B granule (floor).
__device__ __forceinline__ int hswz(int row, int pc) {
    return row * 16 + ((pc + row) & 15);
}
}

// LDS: only the h-planes (raw pixels never touch LDS any more).
//   hA: pixel-pair {mu1_0,mu1_1,mu2_0,mu2_1}, rotate-swizzled.
//   hB: pixel-pair {ss_0,ss_1,xy_0,xy_1}   (ss=conv(x^2+y^2), xy=conv(x*y)).
// 21504 B -> 7 blocks/CU (LDS); VGPR ~80 -> 6 waves/SIMD cap via (256,6).
__global__ __launch_bounds__(256, 6) void ssim_tile_kernel(
        const float* __restrict__ img1, const float* __restrict__ img2,
        double* __restrict__ acc)
{
    __shared__ v4f hA[IN_H * 16];        // 10752 B
    __shared__ v4f hB[IN_H * 16];        // 10752 B
    __shared__ float wred[4];

    const int tid = threadIdx.x;
    const size_t base = (size_t)blockIdx.z * (IMG_W * IMG_H);
    const float* p1 = img1 + base;
    const float* p2 = img2 + base;
    const int x0e = blockIdx.x * TW - 6;    // even
    const int y0  = blockIdx.y * TH - 5;

    // ---- Phase A: fused global->reg load + horizontal 11-tap, 168 threads ----
    // rA = h-row (0..41), gA = col-group (8 output px each).
    // Thread window: 20 px starting at gxb = x0e + 8*gA (even -> 8B-aligned f2).
    // v2f unit m = px {gxb+2m, gxb+2m+1}; output j at px x0+8*gA+j;
    // tap t = k - j - 1, k = 2m+half.
    const int rA = tid >> 2;
    const int gA = tid & 3;
    const bool act2 = tid < 168;
    v2f mu8[8], sx8[8];     // mu8 = {mu1,mu2}; sx8 = {ss, xy}
    if (act2) {
#pragma unroll
        for (int j = 0; j < 8; ++j) { mu8[j] = bcast(0.f); sx8[j] = bcast(0.f); }

        const int gy  = y0 + rA;
        const int gxb = x0e + 8 * gA;
        float2 u1[10], u2[10];
        const bool interior =
            blockIdx.x > 0 && blockIdx.x < gridDim.x - 1 &&
            blockIdx.y > 0 && blockIdx.y < gridDim.y - 1;
        if (interior) {
            const float* r1 = p1 + gy * IMG_W + gxb;
            const float* r2 = p2 + gy * IMG_W + gxb;
#pragma unroll
            for (int m = 0; m < 10; ++m) {
                u1[m] = *(const float2*)(r1 + 2 * m);
                u2[m] = *(const float2*)(r2 + 2 * m);
            }
        } else {
            const bool yok = (gy >= 0) && (gy < IMG_H);
            const float* r1 = p1 + gy * IMG_W;
            const float* r2 = p2 + gy * IMG_W;
#pragma unroll
            for (int m = 0; m < 10; ++m) {
                float a0 = 0.f, a1 = 0.f, b0 = 0.f, b1 = 0.f;
                const int gx = gxb + 2 * m;
                if (yok) {
                    if (gx >= 0 && gx < IMG_W)         { a0 = r1[gx];     b0 = r2[gx]; }
                    if (gx + 1 >= 0 && gx + 1 < IMG_W) { a1 = r1[gx + 1]; b1 = r2[gx + 1]; }
                }
                u1[m].x = a0; u1[m].y = a1;
                u2[m].x = b0; u2[m].y = b1;
            }
        }

#pragma unroll
        for (int m = 0; m < 10; ++m) {
#pragma unroll
            for (int half = 0; half < 2; ++half) {
                const int k = 2 * m + half;
                v2f v;
                v.x = half ? u1[m].y : u1[m].x;
                v.y = half ? u2[m].y : u2[m].x;
                const v2f a2 = pkmul(v, v);
                v2f sx;                           // {x^2+y^2, x*y}
                sx.x = a2.x + a2.y;
                sx.y = v.x * v.y;
#pragma unroll
                for (int j = 0; j < 8; ++j) {
                    const int t = k - j - 1;
                    if (t >= 0 && t < 11) {
                        const v2f w2 = bcast(GW[t]);
                        pkfma(mu8[j], w2, v);
                        pkfma(sx8[j], w2, sx);
                    }
                }
            }
        }
        // transpose {a,b}-packed accs into pixel-pair planes
#pragma unroll
        for (int jp = 0; jp < 4; ++jp) {
            const int j0 = 2 * jp, j1 = 2 * jp + 1;
            v4f A; A.x = mu8[j0].x; A.y = mu8[j1].x; A.z = mu8[j0].y; A.w = mu8[j1].y;
            v4f B; B.x = sx8[j0].x; B.y = sx8[j1].x; B.z = sx8[j0].y; B.w = sx8[j1].y;
            const int e = hswz(rA, 4 * gA + jp);
            hA[e] = A;
            hB[e] = B;
        }
    }
    __syncthreads();

    // ---- Phase 3: vertical 11-tap + SSIM, pixel-pair packed, 128 threads ----
    // 16 pair-cols x 8 row-groups of 4 output rows.
    float lsum = 0.f;
    if (tid < 128) {
        const int pc = tid & 15;
        const int rb = (tid >> 4) * 4;
        v2f m1[4], m2[4], ssA[4], xyA[4];
#pragma unroll
        for (int j = 0; j < 4; ++j) {
            m1[j] = bcast(0.f); m2[j] = bcast(0.f);
            ssA[j] = bcast(0.f); xyA[j] = bcast(0.f);
        }
#pragma unroll
        for (int k = 0; k < 14; ++k) {
            const int e = hswz(rb + k, pc);
            const v4f A = hA[e];
            const v4f B = hB[e];
            const v2f* ah = (const v2f*)&A;
            const v2f* bh = (const v2f*)&B;
#pragma unroll
            for (int j = 0; j < 4; ++j) {
                const int t = k - j;
                if (t >= 0 && t < 11) {
                    const v2f w2 = bcast(GW[t]);
                    pkfma(m1[j],  w2, ah[0]);     // mu1 pair
                    pkfma(m2[j],  w2, ah[1]);     // mu2 pair
                    pkfma(ssA[j], w2, bh[0]);     // ss  pair
                    pkfma(xyA[j], w2, bh[1]);     // xy  pair
                }
            }
        }
        const v2f two  = bcast(2.f);
        const v2f c1p  = bcast(C1c);
        const v2f c2p  = bcast(C2c);
        const v2f neg1 = bcast(-1.f);
#pragma unroll
        for (int j = 0; j < 4; ++j) {
            const v2f mu12 = pkmul(m1[j], m2[j]);
            const v2f sden = pkadd(pkmul(m1[j], m1[j]), pkmul(m2[j], m2[j]));
            const v2f s12  = pkfma3(mu12, neg1, xyA[j]);   // xy - mu1*mu2
            const v2f ssum = pkfma3(sden, neg1, ssA[j]);   // ss - (mu1^2+mu2^2)
            const v2f num  = pkmul(pkfma3(mu12, two, c1p), pkfma3(s12, two, c2p));
            const v2f den  = pkmul(pkadd(sden, c1p), pkadd(ssum, c2p));
            lsum += __fdividef(num.x, den.x) + __fdividef(num.y, den.y);
        }
    }

    // ---- Phase 4: block reduce -> double atomic into 256 ws slots ----
#pragma unroll
    for (int off = 32; off > 0; off >>= 1)
        lsum += __shfl_down(lsum, off, 64);
    if ((tid & 63) == 0) wred[tid >> 6] = lsum;
    __syncthreads();
    if (tid == 0) {
        const int bid = (blockIdx.z * gridDim.y + blockIdx.y) * gridDim.x + blockIdx.x;
        unsafeAtomicAdd(&acc[bid & 255],
                        (double)(wred[0] + wred[1] + wred[2] + wred[3]));
    }
}

__global__ __launch_bounds__(256) void ssim_final_kernel(
        const double* __restrict__ acc, float* __restrict__ out, double inv_total)
{
    const int tid = threadIdx.x;
    double a = acc[tid];
#pragma unroll
    for (int off = 32; off > 0; off >>= 1)
        a += __shfl_down(a, off, 64);
    __shared__ double ws[4];
    if ((tid & 63) == 0) ws[tid >> 6] = a;
    __syncthreads();
    if (tid == 0)
        out[0] = (float)((ws[0] + ws[1] + ws[2] + ws[3]) * inv_total);
}

extern "C" void kernel_launch(void* const* d_in, const int* in_sizes, int n_in,
                              void* d_out, int out_size, void* d_ws, size_t ws_size,
                              hipStream_t stream)
{
    const float* img1 = (const float*)d_in[0];
    const float* img2 = (const float*)d_in[1];
    double* acc = (double*)d_ws;

    hipMemsetAsync(d_ws, 0, 256 * sizeof(double), stream);

    const int nch = in_sizes[0] / (IMG_W * IMG_H);      // 16*3 = 48
    dim3 grid(IMG_W / TW, IMG_H / TH, nch);             // 16 x 16 x 48
    ssim_tile_kernel<<<grid, 256, 0, stream>>>(img1, img2, acc);

    const double inv_total = 1.0 / (double)in_sizes[0];
    ssim_final_kernel<<<1, 256, 0, stream>>>(acc, (float*)d_out, inv_total);
}

// Round 6
// 159.594 us; speedup vs baseline: 1.3706x; 1.3706x over previous
//
#include <hip/hip_runtime.h>

namespace {
constexpr int IMG_W = 512, IMG_H = 512;
constexpr int TW = 32, TH = 32;
constexpr int IN_H = TH + 10;           // 42 staged rows
constexpr float C1c = 0.01f * 0.01f;
constexpr float C2c = 0.03f * 0.03f;

constexpr float GW[11] = {
    1.0283799e-03f, 7.5987582e-03f, 3.6000773e-02f, 1.0936069e-01f,
    2.1300554e-01f, 2.6601172e-01f, 2.1300554e-01f, 1.0936069e-01f,
    3.6000773e-02f, 7.5987582e-03f, 1.0283799e-03f
};

using v2f = __attribute__((ext_vector_type(2))) float;
using v4f = __attribute__((ext_vector_type(4))) float;

// In-place packed FMA, weight in SGPR pair: acc += w * a.
__device__ __forceinline__ void pkfma(v2f& acc, v2f w, v2f a) {
    asm("v_pk_fma_f32 %0, %1, %2, %0" : "+v"(acc) : "s"(w), "v"(a));
}
// d = a*b + c (all VGPR pairs).
__device__ __forceinline__ v2f pkfma3(v2f a, v2f b, v2f c) {
    v2f d;
    asm("v_pk_fma_f32 %0, %1, %2, %3" : "=v"(d) : "v"(a), "v"(b), "v"(c));
    return d;
}
__device__ __forceinline__ v2f pkmul(v2f a, v2f b) {
    v2f d;
    asm("v_pk_mul_f32 %0, %1, %2" : "=v"(d) : "v"(a), "v"(b));
    return d;
}
__device__ __forceinline__ v2f pkadd(v2f a, v2f b) {
    v2f d;
    asm("v_pk_add_f32 %0, %1, %2" : "=v"(d) : "v"(a), "v"(b));
    return d;
}
__device__ __forceinline__ v2f bcast(float w) { v2f r; r.x = w; r.y = w; return r; }

// h-plane rotate swizzle: 16 v4f per row, entry = row*16 + ((pc+row)&15).
// All four LDS access classes of this kernel sit at the wave64-b128
// 8-round floor (verified by bank-residue derivation, R5 post-mortem).
__device__ __forceinline__ int hswz(int row, int pc) {
    return row * 16 + ((pc + row) & 15);
}
}

// LDS union (time-sliced by barriers), 21.5 KB -> 7 blocks/CU:
//   raw: v4f unit c of row r = pixels {x0e+2c, x0e+2c+1} packed {a0,b0,a1,b1},
//        row stride 23 v4f (odd stride -> floor banks in all phases).
//   hA:  pixel-pair {mu1_0,mu1_1,mu2_0,mu2_1}, rotate-swizzled.
//   hB:  pixel-pair {ss_0,ss_1,xy_0,xy_1}   (ss=conv(x^2+y^2), xy=conv(x*y)).
__global__ __launch_bounds__(256, 6) void ssim_tile_kernel(
        const float* __restrict__ img1, const float* __restrict__ img2,
        float* __restrict__ ws, int direct)
{
    union SharedU {
        v4f raw[IN_H * 23];              // 966 v4f = 15456 B
        struct {
            v4f hA[IN_H * 16];           // 672 v4f = 10752 B
            v4f hB[IN_H * 16];           // 672 v4f = 10752 B
        } h;                             // 21504 B total
    };
    __shared__ SharedU u;
    __shared__ float wred[4];

    const int tid = threadIdx.x;
    const size_t base = (size_t)blockIdx.z * (IMG_W * IMG_H);
    const float* p1 = img1 + base;
    const float* p2 = img2 + base;
    const int x0e = blockIdx.x * TW - 6;    // even; window cols = pixels x0e..x0e+43
    const int y0  = blockIdx.y * TH - 5;

    // ---- Phase 1: global -> LDS, 2 pixels/thread, 42x22=924 units, 4 rounds ----
    {
        v4f* s12v4 = u.raw;
        int r   = tid / 22;
        int cf2 = tid - r * 22;
        int goff = (y0 + r) * IMG_W + x0e + 2 * cf2;
        int soff = r * 23 + cf2;
        const bool interior =
            blockIdx.x > 0 && blockIdx.x < gridDim.x - 1 &&
            blockIdx.y > 0 && blockIdx.y < gridDim.y - 1;
        if (interior) {
#pragma unroll
            for (int i = 0; i < 4; ++i) {
                if (i < 3 || tid < 924 - 3 * 256) {     // 156
                    const float2 a = *(const float2*)&p1[goff];
                    const float2 b = *(const float2*)&p2[goff];
                    v4f q; q.x = a.x; q.y = b.x; q.z = a.y; q.w = b.y;
                    s12v4[soff] = q;
                }
                const bool wrap = cf2 + 14 >= 22;
                cf2  += wrap ? -8 : 14;
                r    += wrap ? 12 : 11;
                goff += wrap ? 12 * IMG_W - 16 : 11 * IMG_W + 28;
                soff += wrap ? 12 * 23 - 8     : 11 * 23 + 14;
            }
        } else {
#pragma unroll
            for (int i = 0; i < 4; ++i) {
                if (i < 3 || tid < 924 - 3 * 256) {
                    const int gy = y0 + r;
                    const int gx = x0e + 2 * cf2;
                    float a0 = 0.f, a1 = 0.f, b0 = 0.f, b1 = 0.f;
                    if (gy >= 0 && gy < IMG_H) {
                        if (gx >= 0 && gx < IMG_W)         { a0 = p1[goff];     b0 = p2[goff]; }
                        if (gx + 1 >= 0 && gx + 1 < IMG_W) { a1 = p1[goff + 1]; b1 = p2[goff + 1]; }
                    }
                    v4f q; q.x = a0; q.y = b0; q.z = a1; q.w = b1;
                    s12v4[soff] = q;
                }
                const bool wrap = cf2 + 14 >= 22;
                cf2  += wrap ? -8 : 14;
                r    += wrap ? 12 : 11;
                goff += wrap ? 12 * IMG_W - 16 : 11 * IMG_W + 28;
                soff += wrap ? 12 * 23 - 8     : 11 * 23 + 14;
            }
        }
    }
    __syncthreads();

    // ---- Phase 2: horizontal 11-tap, scatter form ----
    // 42 rows x 4 col-groups x 8 outputs = 168 active threads.
    // v2f window col k = pixel x0e + 8g + k; output j taps t = k - j - 1.
    v2f mu8[8], sx8[8];     // mu8 = {mu1,mu2}; sx8 = {ss, xy}
    const int rA = tid >> 2;
    const int gA = tid & 3;
    const bool act2 = tid < 168;
    if (act2) {
#pragma unroll
        for (int j = 0; j < 8; ++j) { mu8[j] = bcast(0.f); sx8[j] = bcast(0.f); }
        const v4f* srow = u.raw + (rA * 23 + gA * 4);
#pragma unroll
        for (int m = 0; m < 10; ++m) {
            const v4f q = srow[m];
            const v2f* qh = (const v2f*)&q;       // subregister halves, no movs
#pragma unroll
            for (int half = 0; half < 2; ++half) {
                const int k = 2 * m + half;
                const v2f v = qh[half];
                const v2f a2 = pkmul(v, v);
                v2f sx;                           // {x^2+y^2, x*y}
                sx.x = a2.x + a2.y;
                sx.y = v.x * v.y;
#pragma unroll
                for (int j = 0; j < 8; ++j) {
                    const int t = k - j - 1;
                    if (t >= 0 && t < 11) {
                        const v2f w2 = bcast(GW[t]);
                        pkfma(mu8[j], w2, v);
                        pkfma(sx8[j], w2, sx);
                    }
                }
            }
        }
    }
    __syncthreads();            // all raw reads done; safe to overwrite
    if (act2) {
        // transpose {a,b}-packed accs into pixel-pair planes
#pragma unroll
        for (int jp = 0; jp < 4; ++jp) {
            const int j0 = 2 * jp, j1 = 2 * jp + 1;
            v4f A; A.x = mu8[j0].x; A.y = mu8[j1].x; A.z = mu8[j0].y; A.w = mu8[j1].y;
            v4f B; B.x = sx8[j0].x; B.y = sx8[j1].x; B.z = sx8[j0].y; B.w = sx8[j1].y;
            const int e = hswz(rA, 4 * gA + jp);
            u.h.hA[e] = A;
            u.h.hB[e] = B;
        }
    }
    __syncthreads();

    // ---- Phase 3: vertical 11-tap + SSIM, pixel-pair packed, 128 threads ----
    // 16 pair-cols x 8 row-groups of 4 output rows.
    float lsum = 0.f;
    if (tid < 128) {
        const int pc = tid & 15;
        const int rb = (tid >> 4) * 4;
        v2f m1[4], m2[4], ssA[4], xyA[4];
#pragma unroll
        for (int j = 0; j < 4; ++j) {
            m1[j] = bcast(0.f); m2[j] = bcast(0.f);
            ssA[j] = bcast(0.f); xyA[j] = bcast(0.f);
        }
#pragma unroll
        for (int k = 0; k < 14; ++k) {
            const int e = hswz(rb + k, pc);
            const v4f A = u.h.hA[e];
            const v4f B = u.h.hB[e];
            const v2f* ah = (const v2f*)&A;
            const v2f* bh = (const v2f*)&B;
#pragma unroll
            for (int j = 0; j < 4; ++j) {
                const int t = k - j;
                if (t >= 0 && t < 11) {
                    const v2f w2 = bcast(GW[t]);
                    pkfma(m1[j],  w2, ah[0]);     // mu1 pair
                    pkfma(m2[j],  w2, ah[1]);     // mu2 pair
                    pkfma(ssA[j], w2, bh[0]);     // ss  pair
                    pkfma(xyA[j], w2, bh[1]);     // xy  pair
                }
            }
        }
        const v2f two  = bcast(2.f);
        const v2f c1p  = bcast(C1c);
        const v2f c2p  = bcast(C2c);
        const v2f neg1 = bcast(-1.f);
#pragma unroll
        for (int j = 0; j < 4; ++j) {
            const v2f mu12 = pkmul(m1[j], m2[j]);
            const v2f sden = pkadd(pkmul(m1[j], m1[j]), pkmul(m2[j], m2[j]));
            const v2f s12  = pkfma3(mu12, neg1, xyA[j]);   // xy - mu1*mu2
            const v2f ssum = pkfma3(sden, neg1, ssA[j]);   // ss - (mu1^2+mu2^2)
            const v2f num  = pkmul(pkfma3(mu12, two, c1p), pkfma3(s12, two, c2p));
            const v2f den  = pkmul(pkadd(sden, c1p), pkadd(ssum, c2p));
            lsum += __fdividef(num.x, den.x) + __fdividef(num.y, den.y);
        }
    }

    // ---- Phase 4: block reduce -> per-block slot (no init needed) ----
#pragma unroll
    for (int off = 32; off > 0; off >>= 1)
        lsum += __shfl_down(lsum, off, 64);
    if ((tid & 63) == 0) wred[tid >> 6] = lsum;
    __syncthreads();
    if (tid == 0) {
        const int bid = (blockIdx.z * gridDim.y + blockIdx.y) * gridDim.x + blockIdx.x;
        const float tot = wred[0] + wred[1] + wred[2] + wred[3];
        if (direct) ws[bid] = tot;                       // unique slot, no memset
        else        unsafeAtomicAdd(&ws[bid & 255], tot); // fallback (needs memset)
    }
}

__global__ __launch_bounds__(256) void ssim_final_kernel(
        const float* __restrict__ ws, float* __restrict__ out,
        double inv_total, int n)
{
    const int tid = threadIdx.x;
    double a = 0.0;
    for (int i = tid; i < n; i += 256)      // coalesced strided sweep
        a += (double)ws[i];
#pragma unroll
    for (int off = 32; off > 0; off >>= 1)
        a += __shfl_down(a, off, 64);
    __shared__ double red[4];
    if ((tid & 63) == 0) red[tid >> 6] = a;
    __syncthreads();
    if (tid == 0)
        out[0] = (float)((red[0] + red[1] + red[2] + red[3]) * inv_total);
}

extern "C" void kernel_launch(void* const* d_in, const int* in_sizes, int n_in,
                              void* d_out, int out_size, void* d_ws, size_t ws_size,
                              hipStream_t stream)
{
    const float* img1 = (const float*)d_in[0];
    const float* img2 = (const float*)d_in[1];
    float* ws = (float*)d_ws;

    const int nch = in_sizes[0] / (IMG_W * IMG_H);      // 16*3 = 48
    dim3 grid(IMG_W / TW, IMG_H / TH, nch);             // 16 x 16 x 48
    const int nblocks = grid.x * grid.y * grid.z;       // 12288
    const bool direct = ws_size >= (size_t)nblocks * sizeof(float);

    if (!direct)
        hipMemsetAsync(d_ws, 0, 256 * sizeof(float), stream);

    ssim_tile_kernel<<<grid, 256, 0, stream>>>(img1, img2, ws, direct ? 1 : 0);

    const double inv_total = 1.0 / (double)in_sizes[0];
    ssim_final_kernel<<<1, 256, 0, stream>>>(ws, (float*)d_out, inv_total,
                                             direct ? nblocks : 256);
}

// Round 7
// 149.987 us; speedup vs baseline: 1.4584x; 1.0641x over previous
//
#include <hip/hip_runtime.h>

namespace {
constexpr int IMG_W = 512, IMG_H = 512;
constexpr int TW = 32, TH = 32;
constexpr int IN_H = TH + 10;           // 42 staged rows
constexpr float C1c = 0.01f * 0.01f;
constexpr float C2c = 0.03f * 0.03f;

constexpr float GW[11] = {
    1.0283799e-03f, 7.5987582e-03f, 3.6000773e-02f, 1.0936069e-01f,
    2.1300554e-01f, 2.6601172e-01f, 2.1300554e-01f, 1.0936069e-01f,
    3.6000773e-02f, 7.5987582e-03f, 1.0283799e-03f
};

using v2f = __attribute__((ext_vector_type(2))) float;
using v4f = __attribute__((ext_vector_type(4))) float;

// In-place packed FMA, weight in SGPR pair: acc += w * a.
__device__ __forceinline__ void pkfma(v2f& acc, v2f w, v2f a) {
    asm("v_pk_fma_f32 %0, %1, %2, %0" : "+v"(acc) : "s"(w), "v"(a));
}
// d = a*b + c (all VGPR pairs).
__device__ __forceinline__ v2f pkfma3(v2f a, v2f b, v2f c) {
    v2f d;
    asm("v_pk_fma_f32 %0, %1, %2, %3" : "=v"(d) : "v"(a), "v"(b), "v"(c));
    return d;
}
__device__ __forceinline__ v2f pkmul(v2f a, v2f b) {
    v2f d;
    asm("v_pk_mul_f32 %0, %1, %2" : "=v"(d) : "v"(a), "v"(b));
    return d;
}
__device__ __forceinline__ v2f pkadd(v2f a, v2f b) {
    v2f d;
    asm("v_pk_add_f32 %0, %1, %2" : "=v"(d) : "v"(a), "v"(b));
    return d;
}
__device__ __forceinline__ v2f bcast(float w) { v2f r; r.x = w; r.y = w; return r; }

// h-plane rotate swizzle: 16 v4f per row, entry = row*16 + ((pc+row)&15).
// All four LDS access classes of this kernel sit at the wave64-b128
// 8-round floor (verified by bank-residue derivation, R5 post-mortem).
__device__ __forceinline__ int hswz(int row, int pc) {
    return row * 16 + ((pc + row) & 15);
}
}

// LDS union (time-sliced by barriers), 21.5 KB -> 7 blocks/CU:
//   raw: v4f unit c of row r = pixels {x0e+2c, x0e+2c+1} packed {a0,b0,a1,b1},
//        row stride 23 v4f (odd stride -> floor banks in all phases).
//   hA:  pixel-pair {mu1_0,mu1_1,mu2_0,mu2_1}, rotate-swizzled.
//   hB:  pixel-pair {ss_0,ss_1,xy_0,xy_1}   (ss=conv(x^2+y^2), xy=conv(x*y)).
__global__ __launch_bounds__(256, 6) void ssim_tile_kernel(
        const float* __restrict__ img1, const float* __restrict__ img2,
        float* __restrict__ ws, int direct)
{
    union SharedU {
        v4f raw[IN_H * 23];              // 966 v4f = 15456 B
        struct {
            v4f hA[IN_H * 16];           // 672 v4f = 10752 B
            v4f hB[IN_H * 16];           // 672 v4f = 10752 B
        } h;                             // 21504 B total
    };
    __shared__ SharedU u;
    __shared__ float wred[4];

    const int tid = threadIdx.x;
    const size_t base = (size_t)blockIdx.z * (IMG_W * IMG_H);
    const float* p1 = img1 + base;
    const float* p2 = img2 + base;
    const int x0e = blockIdx.x * TW - 6;    // even; window cols = pixels x0e..x0e+43
    const int y0  = blockIdx.y * TH - 5;

    // ---- Phase 1: global -> LDS, 2 pixels/thread, 42x22=924 units, 4 rounds ----
    {
        v4f* s12v4 = u.raw;
        int r   = tid / 22;
        int cf2 = tid - r * 22;
        int goff = (y0 + r) * IMG_W + x0e + 2 * cf2;
        int soff = r * 23 + cf2;
        const bool interior =
            blockIdx.x > 0 && blockIdx.x < gridDim.x - 1 &&
            blockIdx.y > 0 && blockIdx.y < gridDim.y - 1;
        if (interior) {
#pragma unroll
            for (int i = 0; i < 4; ++i) {
                if (i < 3 || tid < 924 - 3 * 256) {     // 156
                    const float2 a = *(const float2*)&p1[goff];
                    const float2 b = *(const float2*)&p2[goff];
                    v4f q; q.x = a.x; q.y = b.x; q.z = a.y; q.w = b.y;
                    s12v4[soff] = q;
                }
                const bool wrap = cf2 + 14 >= 22;
                cf2  += wrap ? -8 : 14;
                r    += wrap ? 12 : 11;
                goff += wrap ? 12 * IMG_W - 16 : 11 * IMG_W + 28;
                soff += wrap ? 12 * 23 - 8     : 11 * 23 + 14;
            }
        } else {
#pragma unroll
            for (int i = 0; i < 4; ++i) {
                if (i < 3 || tid < 924 - 3 * 256) {
                    const int gy = y0 + r;
                    const int gx = x0e + 2 * cf2;
                    float a0 = 0.f, a1 = 0.f, b0 = 0.f, b1 = 0.f;
                    if (gy >= 0 && gy < IMG_H) {
                        if (gx >= 0 && gx < IMG_W)         { a0 = p1[goff];     b0 = p2[goff]; }
                        if (gx + 1 >= 0 && gx + 1 < IMG_W) { a1 = p1[goff + 1]; b1 = p2[goff + 1]; }
                    }
                    v4f q; q.x = a0; q.y = b0; q.z = a1; q.w = b1;
                    s12v4[soff] = q;
                }
                const bool wrap = cf2 + 14 >= 22;
                cf2  += wrap ? -8 : 14;
                r    += wrap ? 12 : 11;
                goff += wrap ? 12 * IMG_W - 16 : 11 * IMG_W + 28;
                soff += wrap ? 12 * 23 - 8     : 11 * 23 + 14;
            }
        }
    }
    __syncthreads();

    // ---- Phase 2: horizontal 11-tap, scatter form ----
    // 42 rows x 4 col-groups x 8 outputs = 168 active threads.
    // v2f window col k = pixel x0e + 8g + k; output j taps t = k - j - 1.
    v2f mu8[8], sx8[8];     // mu8 = {mu1,mu2}; sx8 = {ss, xy}
    const int rA = tid >> 2;
    const int gA = tid & 3;
    const bool act2 = tid < 168;
    if (act2) {
#pragma unroll
        for (int j = 0; j < 8; ++j) { mu8[j] = bcast(0.f); sx8[j] = bcast(0.f); }
        const v4f* srow = u.raw + (rA * 23 + gA * 4);
#pragma unroll
        for (int m = 0; m < 10; ++m) {
            const v4f q = srow[m];
            const v2f* qh = (const v2f*)&q;       // subregister halves, no movs
#pragma unroll
            for (int half = 0; half < 2; ++half) {
                const int k = 2 * m + half;
                const v2f v = qh[half];
                const v2f a2 = pkmul(v, v);
                v2f sx;                           // {x^2+y^2, x*y}
                sx.x = a2.x + a2.y;
                sx.y = v.x * v.y;
#pragma unroll
                for (int j = 0; j < 8; ++j) {
                    const int t = k - j - 1;
                    if (t >= 0 && t < 11) {
                        const v2f w2 = bcast(GW[t]);
                        pkfma(mu8[j], w2, v);
                        pkfma(sx8[j], w2, sx);
                    }
                }
            }
        }
    }
    __syncthreads();            // all raw reads done; safe to overwrite
    if (act2) {
        // transpose {a,b}-packed accs into pixel-pair planes
#pragma unroll
        for (int jp = 0; jp < 4; ++jp) {
            const int j0 = 2 * jp, j1 = 2 * jp + 1;
            v4f A; A.x = mu8[j0].x; A.y = mu8[j1].x; A.z = mu8[j0].y; A.w = mu8[j1].y;
            v4f B; B.x = sx8[j0].x; B.y = sx8[j1].x; B.z = sx8[j0].y; B.w = sx8[j1].y;
            const int e = hswz(rA, 4 * gA + jp);
            u.h.hA[e] = A;
            u.h.hB[e] = B;
        }
    }
    __syncthreads();

    // ---- Phase 3: vertical 11-tap + SSIM, pixel-pair packed, 128 threads ----
    // 16 pair-cols x 8 row-groups of 4 output rows.
    float lsum = 0.f;
    if (tid < 128) {
        const int pc = tid & 15;
        const int rb = (tid >> 4) * 4;
        v2f m1[4], m2[4], ssA[4], xyA[4];
#pragma unroll
        for (int j = 0; j < 4; ++j) {
            m1[j] = bcast(0.f); m2[j] = bcast(0.f);
            ssA[j] = bcast(0.f); xyA[j] = bcast(0.f);
        }
#pragma unroll
        for (int k = 0; k < 14; ++k) {
            const int e = hswz(rb + k, pc);
            const v4f A = u.h.hA[e];
            const v4f B = u.h.hB[e];
            const v2f* ah = (const v2f*)&A;
            const v2f* bh = (const v2f*)&B;
#pragma unroll
            for (int j = 0; j < 4; ++j) {
                const int t = k - j;
                if (t >= 0 && t < 11) {
                    const v2f w2 = bcast(GW[t]);
                    pkfma(m1[j],  w2, ah[0]);     // mu1 pair
                    pkfma(m2[j],  w2, ah[1]);     // mu2 pair
                    pkfma(ssA[j], w2, bh[0]);     // ss  pair
                    pkfma(xyA[j], w2, bh[1]);     // xy  pair
                }
            }
        }
        const v2f two  = bcast(2.f);
        const v2f c1p  = bcast(C1c);
        const v2f c2p  = bcast(C2c);
        const v2f neg1 = bcast(-1.f);
#pragma unroll
        for (int j = 0; j < 4; ++j) {
            const v2f mu12 = pkmul(m1[j], m2[j]);
            const v2f sden = pkadd(pkmul(m1[j], m1[j]), pkmul(m2[j], m2[j]));
            const v2f s12  = pkfma3(mu12, neg1, xyA[j]);   // xy - mu1*mu2
            const v2f ssum = pkfma3(sden, neg1, ssA[j]);   // ss - (mu1^2+mu2^2)
            const v2f num  = pkmul(pkfma3(mu12, two, c1p), pkfma3(s12, two, c2p));
            const v2f den  = pkmul(pkadd(sden, c1p), pkadd(ssum, c2p));
            lsum += __fdividef(num.x, den.x) + __fdividef(num.y, den.y);
        }
    }

    // ---- Phase 4: block reduce -> per-block slot (no init needed) ----
#pragma unroll
    for (int off = 32; off > 0; off >>= 1)
        lsum += __shfl_down(lsum, off, 64);
    if ((tid & 63) == 0) wred[tid >> 6] = lsum;
    __syncthreads();
    if (tid == 0) {
        const int bid = (blockIdx.z * gridDim.y + blockIdx.y) * gridDim.x + blockIdx.x;
        const float tot = wred[0] + wred[1] + wred[2] + wred[3];
        if (direct) ws[bid] = tot;                       // unique slot, no memset
        else        unsafeAtomicAdd(&ws[bid & 255], tot); // fallback (needs memset)
    }
}

// 1 block x 1024 threads (16 waves), float4 loads: 12288 floats = 3072 v4f
// = 3 vector loads/thread. R6's 256-thread scalar version was latency-bound
// (~48 serial loads/thread); this is the fix.
__global__ __launch_bounds__(1024) void ssim_final_kernel(
        const float* __restrict__ ws, float* __restrict__ out,
        double inv_total, int n)
{
    const int tid = threadIdx.x;
    const v4f* w4 = (const v4f*)ws;
    const int n4 = n >> 2;                  // n is a multiple of 4 in both paths
    double a = 0.0;
    for (int i = tid; i < n4; i += 1024) {
        const v4f q = w4[i];
        a += (double)q.x + (double)q.y + (double)q.z + (double)q.w;
    }
#pragma unroll
    for (int off = 32; off > 0; off >>= 1)
        a += __shfl_down(a, off, 64);
    __shared__ double red[16];
    if ((tid & 63) == 0) red[tid >> 6] = a;
    __syncthreads();
    if (tid < 64) {
        double b = (tid < 16) ? red[tid] : 0.0;
#pragma unroll
        for (int off = 8; off > 0; off >>= 1)
            b += __shfl_down(b, off, 64);
        if (tid == 0)
            out[0] = (float)(b * inv_total);
    }
}

extern "C" void kernel_launch(void* const* d_in, const int* in_sizes, int n_in,
                              void* d_out, int out_size, void* d_ws, size_t ws_size,
                              hipStream_t stream)
{
    const float* img1 = (const float*)d_in[0];
    const float* img2 = (const float*)d_in[1];
    float* ws = (float*)d_ws;

    const int nch = in_sizes[0] / (IMG_W * IMG_H);      // 16*3 = 48
    dim3 grid(IMG_W / TW, IMG_H / TH, nch);             // 16 x 16 x 48
    const int nblocks = grid.x * grid.y * grid.z;       // 12288
    const bool direct = ws_size >= (size_t)nblocks * sizeof(float);

    if (!direct)
        hipMemsetAsync(d_ws, 0, 256 * sizeof(float), stream);

    ssim_tile_kernel<<<grid, 256, 0, stream>>>(img1, img2, ws, direct ? 1 : 0);

    const double inv_total = 1.0 / (double)in_sizes[0];
    ssim_final_kernel<<<1, 1024, 0, stream>>>(ws, (float*)d_out, inv_total,
                                              direct ? nblocks : 256);
}